// Round 14
// baseline (133.687 us; speedup 1.0000x reference)
//
#include <hip/hip_runtime.h>
#include <hip/hip_bf16.h>

#define N2 16384
#define D  128
#define PANEL 16384                       // bytes per 128x128 fp8 panel
#define SQC1 1.69864360258810896f         // sqrt(2*log2(e)), folded into zq
#define LN2  0.69314718055994530942f

typedef float f32x4 __attribute__((ext_vector_type(4)));

#if __has_builtin(__builtin_amdgcn_exp2f)
#define EXP2(x) __builtin_amdgcn_exp2f(x)
#else
#define EXP2(x) exp2f(x)
#endif

// f32 -> OCP e4m3fn, RNE. |f| <= ~1.8 here. (R8/R13-proven)
__device__ __forceinline__ unsigned char f2e4m3(float f) {
    union { float f; unsigned u; } v; v.f = f;
    unsigned s = (v.u >> 24) & 0x80;
    int e = (int)((v.u >> 23) & 255) - 127;
    unsigned m = v.u & 0x7fffff;
    if (e < -10) return (unsigned char)s;
    if (e >= -6) {
        unsigned r = m + 0x7ffff + ((m >> 20) & 1);
        unsigned mm = r >> 20;
        int E = e;
        if (mm >= 8) { mm = 0; E += 1; }
        return (unsigned char)(s | ((E + 7) << 3) | (mm & 7));
    }
    float a = fabsf(f) * 512.0f;
    int n = (int)rintf(a);
    return (unsigned char)(s | n);
}

// stage one 16KB fp8 panel global->LDS via global_load_lds width=16 (4 ops).
// LDS dest linear; XOR swizzle pre-applied to GLOBAL source (involution on
// 16B granules); reads use byte ^ ((row&7)<<4), row = byte>>7. (rule #21)
__device__ __forceinline__ void stage16(const char* __restrict__ g,
                                        char* lds, int tid) {
    const int wid = tid >> 6, lane = tid & 63;
    #pragma unroll
    for (int i = 0; i < 4; ++i) {
        int off = (wid << 12) + (i << 10) + (lane << 4);
        int src = off ^ (((off >> 7) & 7) << 4);
        __builtin_amdgcn_global_load_lds(
            (const __attribute__((address_space(1))) unsigned*)(g + src),
            (__attribute__((address_space(3))) unsigned*)(lds + (wid << 12) + (i << 10)),
            16, 0, 0);
    }
}

// ---------- kernel 1: L2-normalize -> fp8; zero rowsum/possum/counter ----------
__global__ void k_norm(const float* __restrict__ z, unsigned char* __restrict__ zq,
                       float* __restrict__ rowsum, float* __restrict__ possum,
                       unsigned* __restrict__ counter) {
    if (blockIdx.x < 64) rowsum[blockIdx.x * 256 + threadIdx.x] = 0.f;
    if (blockIdx.x == 64 && threadIdx.x == 0) { possum[0] = 0.f; counter[0] = 0u; }
    int row  = blockIdx.x * 4 + (threadIdx.x >> 6);
    int lane = threadIdx.x & 63;
    const float2 v = ((const float2*)(z + (size_t)row * D))[lane];
    float ss = v.x * v.x + v.y * v.y;
    #pragma unroll
    for (int m = 1; m < 64; m <<= 1) ss += __shfl_xor(ss, m);
    float inv = SQC1 / fmaxf(sqrtf(ss), 1e-12f);
    unsigned short o = (unsigned short)f2e4m3(v.x * inv)
                     | ((unsigned short)f2e4m3(v.y * inv) << 8);
    ((unsigned short*)(zq + (size_t)row * D))[lane] = o;
}

// K-loop: 4 kk-steps, 16 fp8 MFMA each, into cur
__device__ __forceinline__ void kloop(const char* rbuf, const long (&af)[4][4],
                                      f32x4 (&cur)[4][4], int wc, int l16, int lg) {
    #pragma unroll
    for (int kk = 0; kk < 4; ++kk) {
        long bk[4];
        #pragma unroll
        for (int n = 0; n < 4; ++n) {
            int row = wc * 64 + n * 16 + l16;
            int d = row * 128 + kk * 32 + lg * 8;
            bk[n] = *(const long*)(rbuf + (d ^ ((row & 7) << 4)));
        }
        #pragma unroll
        for (int m = 0; m < 4; ++m)
            #pragma unroll
            for (int n = 0; n < 4; ++n)
                cur[m][n] = __builtin_amdgcn_mfma_f32_16x16x32_fp8_fp8(
                    af[kk][m], bk[n],
                    (kk == 0) ? f32x4{0.f, 0.f, 0.f, 0.f} : cur[m][n], 0, 0, 0);
    }
}

// branchless epilogue main path: e = exp2(prev) = exp(sim); rs += row, cs += col
__device__ __forceinline__ void epi_main(const f32x4 (&prev)[4][4],
                                         float (&rs)[4][4], float (&cs)[4]) {
    #pragma unroll
    for (int m = 0; m < 4; ++m)
        #pragma unroll
        for (int r = 0; r < 4; ++r) {
            float a = 0.f;
            #pragma unroll
            for (int n = 0; n < 4; ++n) {
                float e = EXP2(prev[m][n][r]);
                a += e;
                cs[n] += e;
            }
            rs[m][r] += a;
        }
}

// one pipelined iteration (t >= 1): wait, barrier, stage(t+2), MFMA(t)->cur,
// epilogue(t-1) from prev (interleavable: register-only, no deps on cur),
// then uniform 4-atomic col flush for tile t-1.
__device__ __forceinline__ void iterE(int t, int nt, int sLo, int tileI,
    const char* zb, char* ls, const long (&af)[4][4],
    f32x4 (&cur)[4][4], f32x4 (&prev)[4][4], float (&rs)[4][4],
    float* rowsum, float* possum,
    int tid, int wr, int wc, int l16, int lg, int lane) {
    const int s = sLo + t;
    // counted drain of stage B(t): t==1 -> 4; t==2 or nt-1 -> 8; else 12.
    if (t == 1)                    { asm volatile("s_waitcnt vmcnt(4)"  ::: "memory"); }
    else if (t == 2 || t == nt - 1){ asm volatile("s_waitcnt vmcnt(8)"  ::: "memory"); }
    else                           { asm volatile("s_waitcnt vmcnt(12)" ::: "memory"); }
    __builtin_amdgcn_s_barrier();

    const char* rbuf = ls + ((t % 3) << 14);
    if (t + 2 < nt)
        stage16(zb + (size_t)((tileI + s + 2) & 127) * PANEL,
                ls + (((t + 2) % 3) << 14), tid);

    kloop(rbuf, af, cur, wc, l16, lg);

    // epilogue of tile t-1 (always exists, t>=1); straight-line main path
    float cs[4] = {0.f, 0.f, 0.f, 0.f};
    epi_main(prev, rs, cs);
    const int sPrev = s - 1;
    const int jtp = (tileI + sPrev) & 127;
    if (sPrev == 0) {
        // rare diagonal correction (c==0 blocks, t==1 only): remove self terms,
        // cancel col flush (tile==transpose), extract pos_sim (j = i^1).
        float pp = 0.f;
        #pragma unroll
        for (int m = 0; m < 4; ++m)
            #pragma unroll
            for (int r = 0; r < 4; ++r) {
                if (wr == wc && l16 == (lg * 4 + r))
                    rs[m][r] -= EXP2(prev[m][m][r]);
                if (wr == wc && l16 == ((lg * 4 + r) ^ 1))
                    pp += prev[m][m][r];               // log2-domain pos score
            }
        #pragma unroll
        for (int sh = 1; sh < 64; sh <<= 1) pp += __shfl_xor(pp, sh);
        if (wr == wc && lane == 0) atomicAdd(possum, pp);
        cs[0] = cs[1] = cs[2] = cs[3] = 0.f;
    }
    // uniform col flush: 4 atomic instrs per iteration (vmcnt bookkeeping)
    #pragma unroll
    for (int n = 0; n < 4; ++n) {
        float v = cs[n];
        v += __shfl_xor(v, 16);
        v += __shfl_xor(v, 32);
        if (lg == 0)
            atomicAdd(&rowsum[jtp * 128 + wc * 64 + n * 16 + l16], v);
    }
}

// ---------- kernel 2: symmetric fused sim GEMM (fp8) + pipelined epilogue ----------
// grid (4, 128): s in [16c, 16c+16) (+s=64 for c==3, ti<64). 2 blocks/CU.
// Triple-buffered B (3x16KB), one barrier/tile, counted vmcnt, T15 acc pair.
// Last-finishing block (ticket) does the loss reduce -> 2 graph nodes total.
__global__ __launch_bounds__(256, 2)
void k_sim(const unsigned char* __restrict__ zq, float* __restrict__ rowsum,
           float* __restrict__ possum, unsigned* __restrict__ counter,
           float* __restrict__ out) {
    __shared__ char ls[3 * PANEL];        // 48KB triple buffer
    __shared__ float sm[4];
    __shared__ unsigned ticket;

    const int tileI = blockIdx.y;
    const int c = blockIdx.x;
    const int sLo = c * 16;
    const int nt = (c == 3 && tileI < 64) ? 17 : 16;

    const int tid  = threadIdx.x;
    const int lane = tid & 63, wid = tid >> 6;
    const int wr = wid >> 1, wc = wid & 1;          // 2x2 waves: 64x64 each
    const int l16 = lane & 15, lg = lane >> 4;
    const char* zb = (const char*)zq;

    // prologue: A(ti) -> buf0; pull fp8 A fragments (32 VGPR) to registers
    stage16(zb + (size_t)tileI * PANEL, ls, tid);
    asm volatile("s_waitcnt vmcnt(0)" ::: "memory");
    __builtin_amdgcn_s_barrier();

    long af[4][4];                                     // [kk][m]
    #pragma unroll
    for (int kk = 0; kk < 4; ++kk)
        #pragma unroll
        for (int m = 0; m < 4; ++m) {
            int row = wr * 64 + m * 16 + l16;
            int d = row * 128 + kk * 32 + lg * 8;
            af[kk][m] = *(const long*)(ls + (d ^ ((row & 7) << 4)));
        }
    asm volatile("s_waitcnt lgkmcnt(0)" ::: "memory");
    __builtin_amdgcn_s_barrier();                      // buf0 free for B

    stage16(zb + (size_t)((tileI + sLo) & 127) * PANEL, ls, tid);             // B(0)
    stage16(zb + (size_t)((tileI + sLo + 1) & 127) * PANEL, ls + PANEL, tid); // B(1)

    float rs[4][4];
    #pragma unroll
    for (int m = 0; m < 4; ++m)
        #pragma unroll
        for (int r = 0; r < 4; ++r) rs[m][r] = 0.f;

    f32x4 accA[4][4], accB[4][4];

    // t = 0 (no epilogue yet): drain B(0) (4 newest = B(1)); stage B(2); MFMA
    asm volatile("s_waitcnt vmcnt(4)" ::: "memory");
    __builtin_amdgcn_s_barrier();
    stage16(zb + (size_t)((tileI + sLo + 2) & 127) * PANEL, ls + 2 * PANEL, tid);
    kloop(ls, af, accA, wc, l16, lg);

    // pipelined loop: cur/prev statically swapped (rule #20)
    int t = 1;
    for (; t + 1 < nt; t += 2) {
        iterE(t,     nt, sLo, tileI, zb, ls, af, accB, accA, rs, rowsum, possum,
              tid, wr, wc, l16, lg, lane);
        iterE(t + 1, nt, sLo, tileI, zb, ls, af, accA, accB, rs, rowsum, possum,
              tid, wr, wc, l16, lg, lane);
    }
    if (t < nt)
        iterE(t, nt, sLo, tileI, zb, ls, af, accB, accA, rs, rowsum, possum,
              tid, wr, wc, l16, lg, lane);

    // final epilogue: tile nt-1 (never the diagonal: sLo+nt-1 >= 15)
    {
        float cs[4] = {0.f, 0.f, 0.f, 0.f};
        const int jtp = (tileI + sLo + nt - 1) & 127;
        if (nt & 1) epi_main(accA, rs, cs);
        else        epi_main(accB, rs, cs);
        #pragma unroll
        for (int n = 0; n < 4; ++n) {
            float v = cs[n];
            v += __shfl_xor(v, 16);
            v += __shfl_xor(v, 32);
            if (lg == 0)
                atomicAdd(&rowsum[jtp * 128 + wc * 64 + n * 16 + l16], v);
        }
    }
    // row-sum flush
    #pragma unroll
    for (int m = 0; m < 4; ++m)
        #pragma unroll
        for (int r = 0; r < 4; ++r) {
            float v = rs[m][r];
            v += __shfl_xor(v, 1);
            v += __shfl_xor(v, 2);
            v += __shfl_xor(v, 4);
            v += __shfl_xor(v, 8);
            if (l16 == 0)
                atomicAdd(&rowsum[tileI * 128 + wr * 64 + m * 16 + lg * 4 + r], v);
        }

    // ---- last-block loss reduce (saves a kernel node) ----
    __threadfence();                                   // order my atomics before ticket
    if (tid == 0) ticket = atomicAdd(counter, 1u);
    __syncthreads();
    if (ticket == 511) {                               // all 512 blocks done
        __threadfence();
        float part = 0.f;
        for (int i = tid; i < N2; i += 256)
            part += logf(__hip_atomic_load(&rowsum[i], __ATOMIC_RELAXED,
                                           __HIP_MEMORY_SCOPE_AGENT));
        #pragma unroll
        for (int m = 1; m < 64; m <<= 1) part += __shfl_xor(part, m);
        if (lane == 0) sm[wid] = part;
        __syncthreads();
        if (tid == 0) {
            float ps = __hip_atomic_load(possum, __ATOMIC_RELAXED,
                                         __HIP_MEMORY_SCOPE_AGENT);
            out[0] = (sm[0] + sm[1] + sm[2] + sm[3] - LN2 * ps) * (1.0f / (float)N2);
        }
    }
}

extern "C" void kernel_launch(void* const* d_in, const int* in_sizes, int n_in,
                              void* d_out, int out_size, void* d_ws, size_t ws_size,
                              hipStream_t stream) {
    const float* z = (const float*)d_in[0];
    float* out = (float*)d_out;

    unsigned char* zq = (unsigned char*)d_ws;                         // 2 MiB fp8
    float* rowsum = (float*)((char*)d_ws + (size_t)N2 * D);           // 64 KiB
    float* possum = rowsum + N2;                                      // 4 B
    unsigned* counter = (unsigned*)(possum + 1);                      // 4 B

    k_norm<<<N2 / 4, 256, 0, stream>>>(z, zq, rowsum, possum, counter);
    dim3 grid(4, 128);                                                // s-chunks x i-tiles
    k_sim<<<grid, 256, 0, stream>>>(zq, rowsum, possum, counter, out);
}

// Round 15
// 103.099 us; speedup vs baseline: 1.2967x; 1.2967x over previous
//
#include <hip/hip_runtime.h>
#include <hip/hip_bf16.h>

#define N2 16384
#define D  128
#define PANEL 32768                       // bytes per 128x128 bf16 panel
#define SQC1 1.69864360258810896f         // sqrt(2*log2(e)), folded into zn
#define LN2  0.69314718055994530942f

typedef __bf16 bf16x8 __attribute__((ext_vector_type(8)));
typedef float  f32x4  __attribute__((ext_vector_type(4)));

#if __has_builtin(__builtin_amdgcn_exp2f)
#define EXP2(x) __builtin_amdgcn_exp2f(x)
#else
#define EXP2(x) exp2f(x)
#endif

__device__ __forceinline__ unsigned short f2bf(float f) {
    union { float f; unsigned u; } v; v.f = f;
    unsigned r = v.u + 0x7fffu + ((v.u >> 16) & 1u);
    return (unsigned short)(r >> 16);
}

// stage one 32KB panel global->LDS via global_load_lds width=16.
// LDS dest linear; XOR swizzle on the GLOBAL source (involution); reads
// use byte ^ ((row&7)<<4), row = byte>>8. (rule #21)
__device__ __forceinline__ void stage_panel(const char* __restrict__ g,
                                            char* lds, int tid) {
    const int wid = tid >> 6, lane = tid & 63;
    #pragma unroll
    for (int i = 0; i < 8; ++i) {
        int off = (wid << 13) + (i << 10) + (lane << 4);
        int src = off ^ (((off >> 8) & 7) << 4);
        __builtin_amdgcn_global_load_lds(
            (const __attribute__((address_space(1))) unsigned*)(g + src),
            (__attribute__((address_space(3))) unsigned*)(lds + (wid << 13) + (i << 10)),
            16, 0, 0);
    }
}

// ---------- kernel 1: row L2-normalize -> bf16 sqrt(C1)*zn; zero accumulators ----------
__global__ void k_norm(const float* __restrict__ z, unsigned short* __restrict__ zn,
                       float* __restrict__ rowsum, float* __restrict__ possum,
                       unsigned* __restrict__ counter) {
    if (blockIdx.x < 64) rowsum[blockIdx.x * 256 + threadIdx.x] = 0.f;
    if (blockIdx.x == 64 && threadIdx.x == 0) { possum[0] = 0.f; counter[0] = 0u; }
    int row  = blockIdx.x * 4 + (threadIdx.x >> 6);
    int lane = threadIdx.x & 63;
    const float2 v = ((const float2*)(z + (size_t)row * D))[lane];
    float ss = v.x * v.x + v.y * v.y;
    #pragma unroll
    for (int m = 1; m < 64; m <<= 1) ss += __shfl_xor(ss, m);
    float inv = SQC1 / fmaxf(sqrtf(ss), 1e-12f);
    ushort2 o; o.x = f2bf(v.x * inv); o.y = f2bf(v.y * inv);
    ((ushort2*)(zn + (size_t)row * D))[lane] = o;
}

// ---------- kernel 2: R3's symmetric fused sim GEMM + fused loss reduce ----------
// block (c, ti): s in [16c, 16c+16) (+s=64 for c==3, ti<64). jt=(ti+s)&127.
// A(ti) in regs (staged once); B panels double-buffered in 2x32KB; vmcnt(8)
// counted prefetch; 2 barriers/tile. s=0 diag tile: mask self, extract
// pos_sim in-register (j=i^1). Last-finishing block (ticket) computes the
// final mean loss -> no separate k_loss kernel, no zn re-read.
__global__ __launch_bounds__(256, 2)
void k_sim(const unsigned short* __restrict__ zn, float* __restrict__ rowsum,
           float* __restrict__ possum, unsigned* __restrict__ counter,
           float* __restrict__ out) {
    __shared__ char ls[2 * PANEL];        // 64KB: A prologue via ls0, then B dbuf
    __shared__ float sm[4];
    __shared__ unsigned ticket;
    char* ls0 = ls;
    char* ls1 = ls + PANEL;

    const int tileI = blockIdx.y;
    const int c = blockIdx.x;
    const int sLo = c * 16;
    const int nt = (c == 3 && tileI < 64) ? 17 : 16;

    const int tid  = threadIdx.x;
    const int lane = tid & 63, wid = tid >> 6;
    const int wr = wid >> 1, wc = wid & 1;          // 2x2 waves: 64x64 each
    const int l16 = lane & 15, lg = lane >> 4;
    const char* znb = (const char*)zn;
    const f32x4 ZERO = {0.f, 0.f, 0.f, 0.f};

    // prologue: stage A(ti) -> ls0, pull A fragments to registers
    stage_panel(znb + (size_t)tileI * PANEL, ls0, tid);
    asm volatile("s_waitcnt vmcnt(0)" ::: "memory");
    __builtin_amdgcn_s_barrier();

    bf16x8 af[4][4];                                   // [kk][m]
    #pragma unroll
    for (int kk = 0; kk < 4; ++kk)
        #pragma unroll
        for (int m = 0; m < 4; ++m) {
            int row = wr * 64 + m * 16 + l16;
            int d = row * 256 + kk * 64 + lg * 16;
            af[kk][m] = *(const bf16x8*)(ls0 + (d ^ ((row & 7) << 4)));
        }
    asm volatile("s_waitcnt lgkmcnt(0)" ::: "memory");
    __builtin_amdgcn_s_barrier();                      // ls0 free for B

    stage_panel(znb + (size_t)((tileI + sLo) & 127) * PANEL, ls0, tid);

    float rs[4][4];
    #pragma unroll
    for (int m = 0; m < 4; ++m)
        #pragma unroll
        for (int r = 0; r < 4; ++r) rs[m][r] = 0.f;

    for (int t = 0; t < nt; ++t) {
        const int s  = sLo + t;
        const int jt = (tileI + s) & 127;
        char* rbuf = (t & 1) ? ls1 : ls0;
        char* sbuf = (t & 1) ? ls0 : ls1;
        if (t < nt - 1) {
            stage_panel(znb + (size_t)((tileI + s + 1) & 127) * PANEL, sbuf, tid);
            asm volatile("s_waitcnt vmcnt(8)" ::: "memory");  // B(t) landed
        } else {
            asm volatile("s_waitcnt vmcnt(0)" ::: "memory");
        }
        __builtin_amdgcn_s_barrier();

        bf16x8 bfr[4][4];                              // [kk][n]
        #pragma unroll
        for (int kk = 0; kk < 4; ++kk)
            #pragma unroll
            for (int n = 0; n < 4; ++n) {
                int row = wc * 64 + n * 16 + l16;
                int d = row * 256 + kk * 64 + lg * 16;
                bfr[kk][n] = *(const bf16x8*)(rbuf + (d ^ ((row & 7) << 4)));
            }
        asm volatile("s_waitcnt lgkmcnt(0)" ::: "memory");
        __builtin_amdgcn_s_barrier();                  // rbuf free for next stage

        f32x4 acc[4][4];
        #pragma unroll
        for (int m = 0; m < 4; ++m)
            #pragma unroll
            for (int n = 0; n < 4; ++n)
                acc[m][n] = __builtin_amdgcn_mfma_f32_16x16x32_bf16(af[0][m], bfr[0][n], ZERO, 0, 0, 0);
        #pragma unroll
        for (int kk = 1; kk < 4; ++kk)
            #pragma unroll
            for (int m = 0; m < 4; ++m)
                #pragma unroll
                for (int n = 0; n < 4; ++n)
                    acc[m][n] = __builtin_amdgcn_mfma_f32_16x16x32_bf16(af[kk][m], bfr[kk][n], acc[m][n], 0, 0, 0);

        // epilogue: e = exp2(acc) = exp(sim)
        if (s == 0) {
            // diagonal tile: mask self-sim; extract pos_sim (j = i^1, R14-validated)
            float pp = 0.f;
            #pragma unroll
            for (int m = 0; m < 4; ++m)
                #pragma unroll
                for (int r = 0; r < 4; ++r) {
                    int li = wr * 64 + m * 16 + lg * 4 + r;
                    float a = 0.f;
                    #pragma unroll
                    for (int n = 0; n < 4; ++n) {
                        int lj = wc * 64 + n * 16 + l16;
                        float e = EXP2(acc[m][n][r]);
                        a += (li == lj) ? 0.f : e;
                    }
                    rs[m][r] += a;
                    if (wr == wc && l16 == ((lg * 4 + r) ^ 1))
                        pp += acc[m][m][r];            // log2-domain pos score
                }
            #pragma unroll
            for (int sh = 1; sh < 64; sh <<= 1) pp += __shfl_xor(pp, sh);
            if (wr == wc && lane == 0) atomicAdd(possum, pp);
        } else {
            float cs[4] = {0.f, 0.f, 0.f, 0.f};
            #pragma unroll
            for (int m = 0; m < 4; ++m)
                #pragma unroll
                for (int r = 0; r < 4; ++r) {
                    float a = 0.f;
                    #pragma unroll
                    for (int n = 0; n < 4; ++n) {
                        float e = EXP2(acc[m][n][r]);
                        a += e;
                        cs[n] += e;
                    }
                    rs[m][r] += a;
                }
            // column flush: reduce over the 4 lg row-groups of this wave
            #pragma unroll
            for (int n = 0; n < 4; ++n) {
                float v = cs[n];
                v += __shfl_xor(v, 16);
                v += __shfl_xor(v, 32);
                if (lg == 0)
                    atomicAdd(&rowsum[jt * 128 + wc * 64 + n * 16 + l16], v);
            }
        }
    }

    // row sums -> reduce across 16 column-lanes, one atomic/row
    #pragma unroll
    for (int m = 0; m < 4; ++m)
        #pragma unroll
        for (int r = 0; r < 4; ++r) {
            float v = rs[m][r];
            v += __shfl_xor(v, 1);
            v += __shfl_xor(v, 2);
            v += __shfl_xor(v, 4);
            v += __shfl_xor(v, 8);
            if (l16 == 0)
                atomicAdd(&rowsum[tileI * 128 + wr * 64 + m * 16 + lg * 4 + r], v);
        }

    // ---- last-block loss reduce (R14-validated ticket pattern) ----
    __threadfence();                                   // my atomics visible before ticket
    if (tid == 0) ticket = atomicAdd(counter, 1u);
    __syncthreads();
    if (ticket == 511) {                               // all 512 blocks done
        __threadfence();
        float part = 0.f;
        for (int i = tid; i < N2; i += 256)
            part += logf(__hip_atomic_load(&rowsum[i], __ATOMIC_RELAXED,
                                           __HIP_MEMORY_SCOPE_AGENT));
        #pragma unroll
        for (int m = 1; m < 64; m <<= 1) part += __shfl_xor(part, m);
        if (lane == 0) sm[wid] = part;
        __syncthreads();
        if (tid == 0) {
            float ps = __hip_atomic_load(possum, __ATOMIC_RELAXED,
                                         __HIP_MEMORY_SCOPE_AGENT);
            out[0] = (sm[0] + sm[1] + sm[2] + sm[3] - LN2 * ps) * (1.0f / (float)N2);
        }
    }
}

extern "C" void kernel_launch(void* const* d_in, const int* in_sizes, int n_in,
                              void* d_out, int out_size, void* d_ws, size_t ws_size,
                              hipStream_t stream) {
    const float* z = (const float*)d_in[0];
    float* out = (float*)d_out;

    unsigned short* zn = (unsigned short*)d_ws;                       // 4 MiB
    float* rowsum = (float*)((char*)d_ws + (size_t)N2 * D * 2);       // 64 KiB
    float* possum = rowsum + N2;                                      // 4 B
    unsigned* counter = (unsigned*)(possum + 1);                      // 4 B

    k_norm<<<N2 / 4, 256, 0, stream>>>(z, zn, rowsum, possum, counter);
    dim3 grid(4, 128);                                                // s-chunks x i-tiles
    k_sim<<<grid, 256, 0, stream>>>(zn, rowsum, possum, counter, out);
}

// Round 16
// 101.323 us; speedup vs baseline: 1.3194x; 1.0175x over previous
//
#include <hip/hip_runtime.h>
#include <hip/hip_bf16.h>

#define N2 16384
#define D  128
#define PANEL 32768                       // bytes per 128x128 bf16 panel
#define SQC1 1.69864360258810896f         // sqrt(2*log2(e)), folded into zn
#define LN2  0.69314718055994530942f

typedef __bf16 bf16x8 __attribute__((ext_vector_type(8)));
typedef float  f32x4  __attribute__((ext_vector_type(4)));

#if __has_builtin(__builtin_amdgcn_exp2f)
#define EXP2(x) __builtin_amdgcn_exp2f(x)
#else
#define EXP2(x) exp2f(x)
#endif

__device__ __forceinline__ unsigned short f2bf(float f) {
    union { float f; unsigned u; } v; v.f = f;
    unsigned r = v.u + 0x7fffu + ((v.u >> 16) & 1u);
    return (unsigned short)(r >> 16);
}

// stage one 32KB panel global->LDS via global_load_lds width=16.
// LDS dest linear; XOR swizzle on the GLOBAL source (involution); reads
// use byte ^ ((row&7)<<4), row = byte>>8. (rule #21)
__device__ __forceinline__ void stage_panel(const char* __restrict__ g,
                                            char* lds, int tid) {
    const int wid = tid >> 6, lane = tid & 63;
    #pragma unroll
    for (int i = 0; i < 8; ++i) {
        int off = (wid << 13) + (i << 10) + (lane << 4);
        int src = off ^ (((off >> 8) & 7) << 4);
        __builtin_amdgcn_global_load_lds(
            (const __attribute__((address_space(1))) unsigned*)(g + src),
            (__attribute__((address_space(3))) unsigned*)(lds + (wid << 13) + (i << 10)),
            16, 0, 0);
    }
}

// ---------- kernel 1: row L2-normalize -> bf16 sqrt(C1)*zn; zero accumulators ----------
__global__ void k_norm(const float* __restrict__ z, unsigned short* __restrict__ zn,
                       float* __restrict__ rowsum, float* __restrict__ possum,
                       unsigned* __restrict__ counter) {
    if (blockIdx.x < 64) rowsum[blockIdx.x * 256 + threadIdx.x] = 0.f;
    if (blockIdx.x == 64 && threadIdx.x == 0) { possum[0] = 0.f; counter[0] = 0u; }
    int row  = blockIdx.x * 4 + (threadIdx.x >> 6);
    int lane = threadIdx.x & 63;
    const float2 v = ((const float2*)(z + (size_t)row * D))[lane];
    float ss = v.x * v.x + v.y * v.y;
    #pragma unroll
    for (int m = 1; m < 64; m <<= 1) ss += __shfl_xor(ss, m);
    float inv = SQC1 / fmaxf(sqrtf(ss), 1e-12f);
    ushort2 o; o.x = f2bf(v.x * inv); o.y = f2bf(v.y * inv);
    ((ushort2*)(zn + (size_t)row * D))[lane] = o;
}

// ---------- kernel 2: R3's symmetric fused sim GEMM + fused loss reduce ----------
// block (c, ti): s in [16c, 16c+16) (+s=64 for c==3, ti<64). jt=(ti+s)&127.
// A(ti) in regs (staged once); B panels double-buffered in 2x32KB; vmcnt(8)
// counted prefetch; 2 barriers/tile. s=0 diag tile: mask self, extract
// pos_sim in-register. Last block (ticket) computes the final mean loss.
// LDS kept at EXACTLY 64KB (R15 lesson: +512B crossed the allocation
// granule -> 1 block/CU -> 2x slowdown); sm/ticket alias the head of ls,
// which is dead after the main loop.
__global__ __launch_bounds__(256, 2)
void k_sim(const unsigned short* __restrict__ zn, float* __restrict__ rowsum,
           float* __restrict__ possum, unsigned* __restrict__ counter,
           float* __restrict__ out) {
    __shared__ char ls[2 * PANEL];        // 64KB exactly: A prologue, then B dbuf
    char* ls0 = ls;
    char* ls1 = ls + PANEL;
    float* smf = (float*)ls;              // [0,16): final-reduce scratch (ls dead then)
    unsigned* tick = (unsigned*)(ls + 16);// [16,20): ticket word

    const int tileI = blockIdx.y;
    const int c = blockIdx.x;
    const int sLo = c * 16;
    const int nt = (c == 3 && tileI < 64) ? 17 : 16;

    const int tid  = threadIdx.x;
    const int lane = tid & 63, wid = tid >> 6;
    const int wr = wid >> 1, wc = wid & 1;          // 2x2 waves: 64x64 each
    const int l16 = lane & 15, lg = lane >> 4;
    const char* znb = (const char*)zn;
    const f32x4 ZERO = {0.f, 0.f, 0.f, 0.f};

    // prologue: stage A(ti) -> ls0, pull A fragments to registers
    stage_panel(znb + (size_t)tileI * PANEL, ls0, tid);
    asm volatile("s_waitcnt vmcnt(0)" ::: "memory");
    __builtin_amdgcn_s_barrier();

    bf16x8 af[4][4];                                   // [kk][m]
    #pragma unroll
    for (int kk = 0; kk < 4; ++kk)
        #pragma unroll
        for (int m = 0; m < 4; ++m) {
            int row = wr * 64 + m * 16 + l16;
            int d = row * 256 + kk * 64 + lg * 16;
            af[kk][m] = *(const bf16x8*)(ls0 + (d ^ ((row & 7) << 4)));
        }
    asm volatile("s_waitcnt lgkmcnt(0)" ::: "memory");
    __builtin_amdgcn_s_barrier();                      // ls0 free for B

    stage_panel(znb + (size_t)((tileI + sLo) & 127) * PANEL, ls0, tid);

    float rs[4][4];
    #pragma unroll
    for (int m = 0; m < 4; ++m)
        #pragma unroll
        for (int r = 0; r < 4; ++r) rs[m][r] = 0.f;

    for (int t = 0; t < nt; ++t) {
        const int s  = sLo + t;
        const int jt = (tileI + s) & 127;
        char* rbuf = (t & 1) ? ls1 : ls0;
        char* sbuf = (t & 1) ? ls0 : ls1;
        if (t < nt - 1) {
            stage_panel(znb + (size_t)((tileI + s + 1) & 127) * PANEL, sbuf, tid);
            asm volatile("s_waitcnt vmcnt(8)" ::: "memory");  // B(t) landed
        } else {
            asm volatile("s_waitcnt vmcnt(0)" ::: "memory");
        }
        __builtin_amdgcn_s_barrier();

        bf16x8 bfr[4][4];                              // [kk][n]
        #pragma unroll
        for (int kk = 0; kk < 4; ++kk)
            #pragma unroll
            for (int n = 0; n < 4; ++n) {
                int row = wc * 64 + n * 16 + l16;
                int d = row * 256 + kk * 64 + lg * 16;
                bfr[kk][n] = *(const bf16x8*)(rbuf + (d ^ ((row & 7) << 4)));
            }
        asm volatile("s_waitcnt lgkmcnt(0)" ::: "memory");
        __builtin_amdgcn_s_barrier();                  // rbuf free for next stage

        f32x4 acc[4][4];
        #pragma unroll
        for (int m = 0; m < 4; ++m)
            #pragma unroll
            for (int n = 0; n < 4; ++n)
                acc[m][n] = __builtin_amdgcn_mfma_f32_16x16x32_bf16(af[0][m], bfr[0][n], ZERO, 0, 0, 0);
        #pragma unroll
        for (int kk = 1; kk < 4; ++kk)
            #pragma unroll
            for (int m = 0; m < 4; ++m)
                #pragma unroll
                for (int n = 0; n < 4; ++n)
                    acc[m][n] = __builtin_amdgcn_mfma_f32_16x16x32_bf16(af[kk][m], bfr[kk][n], acc[m][n], 0, 0, 0);

        // epilogue: e = exp2(acc) = exp(sim)
        if (s == 0) {
            // diagonal tile: mask self-sim; extract pos_sim (j = i^1, R14-validated)
            float pp = 0.f;
            #pragma unroll
            for (int m = 0; m < 4; ++m)
                #pragma unroll
                for (int r = 0; r < 4; ++r) {
                    int li = wr * 64 + m * 16 + lg * 4 + r;
                    float a = 0.f;
                    #pragma unroll
                    for (int n = 0; n < 4; ++n) {
                        int lj = wc * 64 + n * 16 + l16;
                        float e = EXP2(acc[m][n][r]);
                        a += (li == lj) ? 0.f : e;
                    }
                    rs[m][r] += a;
                    if (wr == wc && l16 == ((lg * 4 + r) ^ 1))
                        pp += acc[m][m][r];            // log2-domain pos score
                }
            #pragma unroll
            for (int sh = 1; sh < 64; sh <<= 1) pp += __shfl_xor(pp, sh);
            if (wr == wc && lane == 0) atomicAdd(possum, pp);
        } else {
            float cs[4] = {0.f, 0.f, 0.f, 0.f};
            #pragma unroll
            for (int m = 0; m < 4; ++m)
                #pragma unroll
                for (int r = 0; r < 4; ++r) {
                    float a = 0.f;
                    #pragma unroll
                    for (int n = 0; n < 4; ++n) {
                        float e = EXP2(acc[m][n][r]);
                        a += e;
                        cs[n] += e;
                    }
                    rs[m][r] += a;
                }
            // column flush: reduce over the 4 lg row-groups of this wave
            #pragma unroll
            for (int n = 0; n < 4; ++n) {
                float v = cs[n];
                v += __shfl_xor(v, 16);
                v += __shfl_xor(v, 32);
                if (lg == 0)
                    atomicAdd(&rowsum[jt * 128 + wc * 64 + n * 16 + l16], v);
            }
        }
    }

    // row sums -> reduce across 16 column-lanes, one atomic/row
    #pragma unroll
    for (int m = 0; m < 4; ++m)
        #pragma unroll
        for (int r = 0; r < 4; ++r) {
            float v = rs[m][r];
            v += __shfl_xor(v, 1);
            v += __shfl_xor(v, 2);
            v += __shfl_xor(v, 4);
            v += __shfl_xor(v, 8);
            if (l16 == 0)
                atomicAdd(&rowsum[tileI * 128 + wr * 64 + m * 16 + lg * 4 + r], v);
        }

    // ---- last-block loss reduce (ticket; ls is dead, alias its head) ----
    __builtin_amdgcn_s_barrier();                      // all ls reads retired
    __threadfence();                                   // my atomics visible
    if (tid == 0) *tick = atomicAdd(counter, 1u);
    __syncthreads();
    if (*tick == 511) {                                // all 512 blocks done
        __threadfence();
        float part = 0.f;
        for (int i = tid; i < N2; i += 256)
            part += logf(__hip_atomic_load(&rowsum[i], __ATOMIC_RELAXED,
                                           __HIP_MEMORY_SCOPE_AGENT));
        #pragma unroll
        for (int m = 1; m < 64; m <<= 1) part += __shfl_xor(part, m);
        if (lane == 0) smf[wid] = part;
        __syncthreads();
        if (tid == 0) {
            float ps = __hip_atomic_load(possum, __ATOMIC_RELAXED,
                                         __HIP_MEMORY_SCOPE_AGENT);
            out[0] = (smf[0] + smf[1] + smf[2] + smf[3] - LN2 * ps) * (1.0f / (float)N2);
        }
    }
}

extern "C" void kernel_launch(void* const* d_in, const int* in_sizes, int n_in,
                              void* d_out, int out_size, void* d_ws, size_t ws_size,
                              hipStream_t stream) {
    const float* z = (const float*)d_in[0];
    float* out = (float*)d_out;

    unsigned short* zn = (unsigned short*)d_ws;                       // 4 MiB
    float* rowsum = (float*)((char*)d_ws + (size_t)N2 * D * 2);       // 64 KiB
    float* possum = rowsum + N2;                                      // 4 B
    unsigned* counter = (unsigned*)(possum + 1);                      // 4 B

    k_norm<<<N2 / 4, 256, 0, stream>>>(z, zn, rowsum, possum, counter);
    dim3 grid(4, 128);                                                // s-chunks x i-tiles
    k_sim<<<grid, 256, 0, stream>>>(zn, rowsum, possum, counter, out);
}

// Round 17
// 61.241 us; speedup vs baseline: 2.1829x; 1.6545x over previous
//
#include <hip/hip_runtime.h>
#include <hip/hip_bf16.h>

#define N2 16384
#define D  128
#define PANEL 32768                       // bytes per 128x128 bf16 panel
#define SQC1 1.69864360258810896f         // sqrt(2*log2(e)), folded into zn
#define LN2  0.69314718055994530942f

typedef __bf16 bf16x8 __attribute__((ext_vector_type(8)));
typedef float  f32x4  __attribute__((ext_vector_type(4)));

#if __has_builtin(__builtin_amdgcn_exp2f)
#define EXP2(x) __builtin_amdgcn_exp2f(x)
#else
#define EXP2(x) exp2f(x)
#endif

__device__ __forceinline__ unsigned short f2bf(float f) {
    union { float f; unsigned u; } v; v.f = f;
    unsigned r = v.u + 0x7fffu + ((v.u >> 16) & 1u);
    return (unsigned short)(r >> 16);
}

// stage one 32KB panel global->LDS via global_load_lds width=16.
// LDS dest linear; XOR swizzle on the GLOBAL source (involution); reads
// use byte ^ ((row&7)<<4). (rule #21)
__device__ __forceinline__ void stage_panel(const char* __restrict__ g,
                                            char* lds, int tid) {
    const int wid = tid >> 6, lane = tid & 63;
    #pragma unroll
    for (int i = 0; i < 8; ++i) {
        int off = (wid << 13) + (i << 10) + (lane << 4);
        int src = off ^ (((off >> 8) & 7) << 4);
        __builtin_amdgcn_global_load_lds(
            (const __attribute__((address_space(1))) unsigned*)(g + src),
            (__attribute__((address_space(3))) unsigned*)(lds + (wid << 13) + (i << 10)),
            16, 0, 0);
    }
}

// ---------- kernel 1: row L2-normalize -> bf16 sqrt(C1)*zn, + zero rowsum/out ----------
// (R5-validated zero-folding: replaces the two hipMemsetAsync nodes)
__global__ void k_norm(const float* __restrict__ z, unsigned short* __restrict__ zn,
                       float* __restrict__ rowsum, float* __restrict__ out) {
    if (blockIdx.x < 64) rowsum[blockIdx.x * 256 + threadIdx.x] = 0.f;
    if (blockIdx.x == 64 && threadIdx.x == 0) out[0] = 0.f;
    int row  = blockIdx.x * 4 + (threadIdx.x >> 6);
    int lane = threadIdx.x & 63;
    const float2 v = ((const float2*)(z + (size_t)row * D))[lane];
    float ss = v.x * v.x + v.y * v.y;
    #pragma unroll
    for (int m = 1; m < 64; m <<= 1) ss += __shfl_xor(ss, m);
    float inv = SQC1 / fmaxf(sqrtf(ss), 1e-12f);
    ushort2 o; o.x = f2bf(v.x * inv); o.y = f2bf(v.y * inv);
    ((ushort2*)(zn + (size_t)row * D))[lane] = o;
}

// ---------- kernel 2: R3's symmetric fused sim GEMM + exp row/col sums ----------
// (byte-identical to the 52.3us R3 kernel; no pos extraction, no ticket)
// block (c, ti): s in [16c, 16c+16) (+s=64 for c==3, ti<64). jt=(ti+s)&127.
__global__ __launch_bounds__(256, 2)
void k_sim(const unsigned short* __restrict__ zn, float* __restrict__ rowsum) {
    __shared__ unsigned short ls[2][PANEL / 2];
    char* ls0 = (char*)&ls[0][0];
    char* ls1 = (char*)&ls[1][0];

    const int tileI = blockIdx.y;
    const int sBase = blockIdx.x * 16;
    const int nt = (blockIdx.x == 3 && tileI < 64) ? 17 : 16;
    const int tid  = threadIdx.x;
    const int lane = tid & 63, wid = tid >> 6;
    const int wr = wid >> 1, wc = wid & 1;          // 2x2 wave grid, 64x64 each
    const int l16 = lane & 15, lg = lane >> 4;
    const char* znb = (const char*)zn;
    const f32x4 ZERO = {0.f, 0.f, 0.f, 0.f};

    // prologue: stage A(ti) -> ls0, B(s=sBase) -> ls1
    stage_panel(znb + (size_t)tileI * PANEL, ls0, tid);
    stage_panel(znb + (size_t)((tileI + sBase) & 127) * PANEL, ls1, tid);
    asm volatile("s_waitcnt vmcnt(8)" ::: "memory");   // A landed
    __builtin_amdgcn_s_barrier();

    // A fragments -> registers (reused for all tiles)
    bf16x8 af[4][4];                                   // [kk][m]
    #pragma unroll
    for (int kk = 0; kk < 4; ++kk)
        #pragma unroll
        for (int m = 0; m < 4; ++m) {
            int row = wr * 64 + m * 16 + l16;
            int d = row * 256 + kk * 64 + lg * 16;
            af[kk][m] = *(const bf16x8*)(ls0 + (d ^ ((row & 7) << 4)));
        }
    asm volatile("s_waitcnt lgkmcnt(0)" ::: "memory");
    __builtin_amdgcn_s_barrier();                      // ls0 now reusable

    float rs[4][4];
    #pragma unroll
    for (int m = 0; m < 4; ++m)
        #pragma unroll
        for (int r = 0; r < 4; ++r) rs[m][r] = 0.f;

    for (int t = 0; t < nt; ++t) {
        const int s  = sBase + t;
        const int jt = (tileI + s) & 127;
        char* rbuf = (t & 1) ? ls0 : ls1;              // B(s)
        char* sbuf = (t & 1) ? ls1 : ls0;              // B(s+1) dest
        if (t < nt - 1) {
            stage_panel(znb + (size_t)((tileI + s + 1) & 127) * PANEL, sbuf, tid);
            asm volatile("s_waitcnt vmcnt(8)" ::: "memory");  // B(s) landed
        } else {
            asm volatile("s_waitcnt vmcnt(0)" ::: "memory");
        }
        __builtin_amdgcn_s_barrier();

        bf16x8 bfr[4][4];                              // [kk][n]
        #pragma unroll
        for (int kk = 0; kk < 4; ++kk)
            #pragma unroll
            for (int n = 0; n < 4; ++n) {
                int row = wc * 64 + n * 16 + l16;
                int d = row * 256 + kk * 64 + lg * 16;
                bfr[kk][n] = *(const bf16x8*)(rbuf + (d ^ ((row & 7) << 4)));
            }
        asm volatile("s_waitcnt lgkmcnt(0)" ::: "memory");
        __builtin_amdgcn_s_barrier();                  // rbuf free for next stage

        f32x4 acc[4][4];
        #pragma unroll
        for (int m = 0; m < 4; ++m)
            #pragma unroll
            for (int n = 0; n < 4; ++n)
                acc[m][n] = __builtin_amdgcn_mfma_f32_16x16x32_bf16(af[0][m], bfr[0][n], ZERO, 0, 0, 0);
        #pragma unroll
        for (int kk = 1; kk < 4; ++kk)
            #pragma unroll
            for (int m = 0; m < 4; ++m)
                #pragma unroll
                for (int n = 0; n < 4; ++n)
                    acc[m][n] = __builtin_amdgcn_mfma_f32_16x16x32_bf16(af[kk][m], bfr[kk][n], acc[m][n], 0, 0, 0);

        // epilogue: e = exp2(acc) = exp(sim); rows accumulate in regs,
        // cols flushed per tile (jt changes every tile).
        if (s == 0) {
            // diagonal tile: mask self-sim, row sums only
            #pragma unroll
            for (int m = 0; m < 4; ++m)
                #pragma unroll
                for (int r = 0; r < 4; ++r) {
                    int li = wr * 64 + m * 16 + lg * 4 + r;
                    float a = 0.f;
                    #pragma unroll
                    for (int n = 0; n < 4; ++n) {
                        int lj = wc * 64 + n * 16 + l16;
                        float e = EXP2(acc[m][n][r]);
                        a += (li == lj) ? 0.f : e;
                    }
                    rs[m][r] += a;
                }
        } else {
            float cs[4] = {0.f, 0.f, 0.f, 0.f};
            #pragma unroll
            for (int m = 0; m < 4; ++m)
                #pragma unroll
                for (int r = 0; r < 4; ++r) {
                    float a = 0.f;
                    #pragma unroll
                    for (int n = 0; n < 4; ++n) {
                        float e = EXP2(acc[m][n][r]);
                        a += e;
                        cs[n] += e;
                    }
                    rs[m][r] += a;
                }
            // column flush: reduce over the 4 lg row-groups of this wave
            #pragma unroll
            for (int n = 0; n < 4; ++n) {
                float v = cs[n];
                v += __shfl_xor(v, 16);
                v += __shfl_xor(v, 32);
                if (lg == 0)
                    atomicAdd(&rowsum[jt * 128 + wc * 64 + n * 16 + l16], v);
            }
        }
    }

    // final: row sums -> reduce across 16 column-lanes, one atomic/row
    #pragma unroll
    for (int m = 0; m < 4; ++m)
        #pragma unroll
        for (int r = 0; r < 4; ++r) {
            float v = rs[m][r];
            v += __shfl_xor(v, 1);
            v += __shfl_xor(v, 2);
            v += __shfl_xor(v, 4);
            v += __shfl_xor(v, 8);
            if (l16 == 0)
                atomicAdd(&rowsum[tileI * 128 + wr * 64 + m * 16 + lg * 4 + r], v);
        }
}

// ---------- kernel 3: fused loss + mean (R3-verbatim) ----------
// mean loss = (1/N2) * [ sum_i ln(rowsum_i) - ln2 * sum_{i,k} zn'[i][k]*zn'[i^1][k] ]
__global__ void k_loss_reduce(const unsigned short* __restrict__ zn,
                              const float* __restrict__ rowsum,
                              float* __restrict__ out) {
    const int tid = threadIdx.x + blockIdx.x * 256;   // 64 blocks x 256
    float p = 0.f;
    const bf16x8* v8 = (const bf16x8*)zn;
    for (int v = tid; v < N2 * D / 8; v += 64 * 256) {
        bf16x8 a = v8[v];
        bf16x8 b = v8[v ^ 16];                        // row i^1, same k-slice
        #pragma unroll
        for (int e = 0; e < 8; ++e) p += (float)a[e] * (float)b[e];
    }
    float part = logf(rowsum[tid]) - LN2 * p;         // exactly one row per thread

    __shared__ float sm[4];
    #pragma unroll
    for (int m = 1; m < 64; m <<= 1) part += __shfl_xor(part, m);
    if ((threadIdx.x & 63) == 0) sm[threadIdx.x >> 6] = part;
    __syncthreads();
    if (threadIdx.x == 0)
        atomicAdd(out, (sm[0] + sm[1] + sm[2] + sm[3]) * (1.0f / (float)N2));
}

extern "C" void kernel_launch(void* const* d_in, const int* in_sizes, int n_in,
                              void* d_out, int out_size, void* d_ws, size_t ws_size,
                              hipStream_t stream) {
    const float* z = (const float*)d_in[0];
    float* out = (float*)d_out;

    unsigned short* zn = (unsigned short*)d_ws;                       // 4 MiB
    float* rowsum = (float*)((char*)d_ws + (size_t)N2 * D * 2);       // 64 KiB

    k_norm<<<N2 / 4, 256, 0, stream>>>(z, zn, rowsum, out);
    dim3 grid(4, 128);                                                // s-chunks x i-tiles
    k_sim<<<grid, 256, 0, stream>>>(zn, rowsum);
    k_loss_reduce<<<64, 256, 0, stream>>>(zn, rowsum, out);
}